// Round 5
// baseline (143.709 us; speedup 1.0000x reference)
//
#include <hip/hip_runtime.h>
#include <stdint.h>

#define NROWS 8192
#define MCOLS 8192
#define DDIM  64
#define NBX   32     // grid.x (col-tile blocks) -> partials per row
#define NBY   64     // grid.y (row-tile blocks) -> partials per col

typedef _Float16 half8   __attribute__((ext_vector_type(8)));
typedef float    floatx4 __attribute__((ext_vector_type(4)));

// ---------- monotone float <-> uint key (for max-reduce argmax) ----------
__device__ __forceinline__ unsigned f2key(float f) {
  unsigned u = __float_as_uint(f);
  return (u & 0x80000000u) ? ~u : (u | 0x80000000u);
}
__device__ __forceinline__ float key2f(unsigned k) {
  unsigned u = (k & 0x80000000u) ? (k & 0x7fffffffu) : ~k;
  return __uint_as_float(u);
}

// ---------- fused: fp16-split conversion + row norms ----------
__global__ void convert_kernel(const float* __restrict__ x, const float* __restrict__ y,
                               _Float16* __restrict__ xh, _Float16* __restrict__ xl,
                               _Float16* __restrict__ yh, _Float16* __restrict__ yl,
                               float* __restrict__ xn, float* __restrict__ yn) {
  __shared__ float lnorm[32];
  const int gid = blockIdx.x * 256 + threadIdx.x;      // 0 .. 131071
  if (threadIdx.x < 32) lnorm[threadIdx.x] = 0.0f;
  __syncthreads();

  const float* src; _Float16 *dh, *dl; float* nout; int t, rowbase;
  if (gid < 65536) { src = x; dh = xh; dl = xl; nout = xn; t = gid;
                     rowbase = blockIdx.x * 32; }
  else             { src = y; dh = yh; dl = yl; nout = yn; t = gid - 65536;
                     rowbase = (blockIdx.x - 256) * 32; }

  const int lane = t & 63;
  const int c    = (t >> 6) & 1;
  const int p    = t >> 7;
  const int row  = p * 16 + (lane & 15);
  const int k0   = c * 32 + ((lane >> 4) << 3);
  const float* s = src + (size_t)row * DDIM + k0;

  float fb[8];
  *(floatx4*)(&fb[0]) = *(const floatx4*)(s);
  *(floatx4*)(&fb[4]) = *(const floatx4*)(s + 4);

  _Float16 hbuf[8], lbuf[8];
  float s8 = 0.0f;
  #pragma unroll
  for (int j = 0; j < 8; ++j) {
    float f = fb[j];
    _Float16 h = (_Float16)f;
    hbuf[j] = h;
    lbuf[j] = (_Float16)((f - (float)h) * 2048.0f);
    s8 = fmaf(f, f, s8);
  }
  size_t o = (size_t)t * 8;
  *(half8*)(dh + o) = *(half8*)hbuf;
  *(half8*)(dl + o) = *(half8*)lbuf;

  atomicAdd(&lnorm[((p & 1) << 4) | (t & 15)], s8);
  __syncthreads();
  if (threadIdx.x < 32) nout[rowbase + threadIdx.x] = lnorm[threadIdx.x];
}

#define MFMA16(A, B, C) __builtin_amdgcn_mfma_f32_16x16x32_f16((A), (B), (C), 0, 0, 0)

// ---------- main pass: block = 4 waves, each wave 32 rows x 256 cols ----------
// Round-5 change: __launch_bounds__(256, 4) — force the allocator to <=128
// unified regs/wave so 4 waves/SIMD can reside (est. live set ~112: 80 arch +
// 32 accum).  27% occupancy (2.2 waves/SIMD) left sqrt/exp chains, DS-atomic
// drains and MFMA waits exposed (~35% no-issue gap).  Everything else as the
// measured-best round-4 version.
__global__ __launch_bounds__(256, 4) void mfma_tile_kernel(
    const _Float16* __restrict__ xh, const _Float16* __restrict__ xl,
    const _Float16* __restrict__ yh, const _Float16* __restrict__ yl,
    const float* __restrict__ xn, const float* __restrict__ yn,
    unsigned long long* __restrict__ row_part_key, float* __restrict__ row_part_sum,
    unsigned long long* __restrict__ col_part_key, float* __restrict__ col_part_sum)
{
  __shared__ unsigned long long lkey[256];   // per-block col keys (2 KB)
  __shared__ float              lsum[256];   // per-block col sums (1 KB)

  const int wave = threadIdx.x >> 6;
  const int lane = threadIdx.x & 63;
  const int l15  = lane & 15;
  const int g    = lane >> 4;                // row-group 0..3
  const int ap0  = blockIdx.y * 8 + wave * 2;       // first of 2 A panels
  const int ro   = ap0 * 16 + g * 4;                // first row this lane covers
  const int colbase = blockIdx.x * 256;

  lkey[threadIdx.x] = 0ull;
  lsum[threadIdx.x] = 0.0f;
  __syncthreads();

  // ---- A fragments: 2 panels x (2 hi + 2 lo chunks), 32 VGPRs ----
  const half8* xh8 = (const half8*)xh;
  const half8* xl8 = (const half8*)xl;
  const half8* yh8 = (const half8*)yh;
  const half8* yl8 = (const half8*)yl;
  const size_t a0 = (size_t)ap0 * 128 + lane;
  half8 Ah[2][2], Al[2][2];
  #pragma unroll
  for (int p = 0; p < 2; ++p) {
    Ah[p][0] = xh8[a0 + p * 128];      Ah[p][1] = xh8[a0 + p * 128 + 64];
    Al[p][0] = xl8[a0 + p * 128];      Al[p][1] = xl8[a0 + p * 128 + 64];
  }

  // ---- per-row state: 8 rows/lane ----
  float xne[8], rsum[8], rmax[8]; int ridx[8];
  #pragma unroll
  for (int s = 0; s < 8; ++s) {
    xne[s]  = xn[ro + ((s >> 2) << 4) + (s & 3)];
    rsum[s] = 0.0f; rmax[s] = -3.4e38f; ridx[s] = 0;
  }

  const size_t bcol0 = (size_t)(blockIdx.x * 16) * 128 + lane;

  // ---- double-buffered B fragments + column norms ----
  half8 b0h0, b0h1, b0l0, b0l1; float y0n;
  half8 b1h0, b1h1, b1l0, b1l1; float y1n;
  b0h0 = yh8[bcol0];        b0h1 = yh8[bcol0 + 64];
  b0l0 = yl8[bcol0];        b0l1 = yl8[bcol0 + 64];
  y0n  = yn[colbase + l15];
  b1h0 = yh8[bcol0 + 128];  b1h1 = yh8[bcol0 + 192];
  b1l0 = yl8[bcol0 + 128];  b1l1 = yl8[bcol0 + 192];
  y1n  = yn[colbase + 16 + l15];

#define MFMA_TILE(BH0, BH1, BL0, BL1, O1A, O2A, O1B, O2B)                      \
  {                                                                            \
    floatx4 c1_ = {}, c2_ = {};                                                \
    c1_ = MFMA16(Ah[0][0], BH0, c1_);                                          \
    c1_ = MFMA16(Ah[0][1], BH1, c1_);                                          \
    c2_ = MFMA16(Al[0][0], BH0, c2_);                                          \
    c2_ = MFMA16(Al[0][1], BH1, c2_);                                          \
    c2_ = MFMA16(Ah[0][0], BL0, c2_);                                          \
    c2_ = MFMA16(Ah[0][1], BL1, c2_);                                          \
    O1A = c1_; O2A = c2_;                                                      \
    floatx4 d1_ = {}, d2_ = {};                                                \
    d1_ = MFMA16(Ah[1][0], BH0, d1_);                                          \
    d1_ = MFMA16(Ah[1][1], BH1, d1_);                                          \
    d2_ = MFMA16(Al[1][0], BH0, d2_);                                          \
    d2_ = MFMA16(Al[1][1], BH1, d2_);                                          \
    d2_ = MFMA16(Ah[1][0], BL0, d2_);                                          \
    d2_ = MFMA16(Ah[1][1], BL1, d2_);                                          \
    O1B = d1_; O2B = d2_;                                                      \
  }

#define EPILOGUE(JT, C1A, C2A, C1B, C2B, YNC)                                  \
  {                                                                            \
    const int col_ = colbase + (JT) * 16 + l15;                                \
    float cmax_ = -3.4e38f; int cidx_ = 0;                                     \
    float epan0_, epan1_;                                                      \
    {                                                                          \
      float ee_[4];                                                            \
      _Pragma("unroll")                                                        \
      for (int r = 0; r < 4; ++r) {                                            \
        const int s_ = r;                                                      \
        float dot = fmaf(C2A[r], (1.0f / 2048.0f), C1A[r]);                    \
        float sq  = fmaxf(fmaf(-2.0f, dot, xne[s_] + (YNC)), 0.0f);            \
        float d   = 2.0f - __builtin_amdgcn_sqrtf(sq);                         \
        float e   = __expf(d);                                                 \
        rsum[s_] += e;                                                         \
        if (d > rmax[s_]) ridx[s_] = col_;   /* cols ascend -> first max */    \
        rmax[s_] = fmaxf(rmax[s_], d);                                         \
        if (d > cmax_) cidx_ = s_;           /* rows ascend -> first max */    \
        cmax_ = fmaxf(cmax_, d);                                               \
        ee_[r] = e;                                                            \
      }                                                                        \
      epan0_ = (ee_[0] + ee_[1]) + (ee_[2] + ee_[3]);                          \
    }                                                                          \
    {                                                                          \
      float ee_[4];                                                            \
      _Pragma("unroll")                                                        \
      for (int r = 0; r < 4; ++r) {                                            \
        const int s_ = 4 + r;                                                  \
        float dot = fmaf(C2B[r], (1.0f / 2048.0f), C1B[r]);                    \
        float sq  = fmaxf(fmaf(-2.0f, dot, xne[s_] + (YNC)), 0.0f);            \
        float d   = 2.0f - __builtin_amdgcn_sqrtf(sq);                         \
        float e   = __expf(d);                                                 \
        rsum[s_] += e;                                                         \
        if (d > rmax[s_]) ridx[s_] = col_;                                     \
        rmax[s_] = fmaxf(rmax[s_], d);                                         \
        if (d > cmax_) cidx_ = s_;                                             \
        cmax_ = fmaxf(cmax_, d);                                               \
        ee_[r] = e;                                                            \
      }                                                                        \
      epan1_ = (ee_[0] + ee_[1]) + (ee_[2] + ee_[3]);                          \
    }                                                                          \
    float csum_ = epan0_ + epan1_;         /* same sum tree as before */       \
    int crow_ = ro + ((cidx_ >> 2) << 4) + (cidx_ & 3);                        \
    unsigned long long ckey_ =                                                 \
        ((unsigned long long)f2key(cmax_) << 32) |                             \
        (unsigned long long)(unsigned)(~(unsigned)crow_);                      \
    atomicMax(&lkey[(JT) * 16 + l15], ckey_);   /* ds_max_u64 */               \
    atomicAdd(&lsum[(JT) * 16 + l15], csum_);   /* ds_add_f32 */               \
  }

  // ---- results pipeline: P = current tile, Q = next tile ----
  floatx4 Pc1a, Pc2a, Pc1b, Pc2b;
  floatx4 Qc1a, Qc2a, Qc1b, Qc2b;

  MFMA_TILE(b0h0, b0h1, b0l0, b0l1, Pc1a, Pc2a, Pc1b, Pc2b);   // tile 0

  for (int jt = 0; jt < 14; jt += 2) {
    // even step: MFMA tile jt+1 (buf1), epilogue tile jt (P), prefetch jt+2->buf0
    {
      float ycur = y0n;
      const size_t bn = bcol0 + (size_t)(jt + 2) * 128;
      b0h0 = yh8[bn];      b0h1 = yh8[bn + 64];
      b0l0 = yl8[bn];      b0l1 = yl8[bn + 64];
      y0n  = yn[colbase + (jt + 2) * 16 + l15];
      MFMA_TILE(b1h0, b1h1, b1l0, b1l1, Qc1a, Qc2a, Qc1b, Qc2b);
      EPILOGUE(jt, Pc1a, Pc2a, Pc1b, Pc2b, ycur);
    }
    // odd step: MFMA tile jt+2 (buf0), epilogue tile jt+1 (Q), prefetch jt+3->buf1
    {
      float ycur = y1n;
      const size_t bn = bcol0 + (size_t)(jt + 3) * 128;
      b1h0 = yh8[bn];      b1h1 = yh8[bn + 64];
      b1l0 = yl8[bn];      b1l1 = yl8[bn + 64];
      y1n  = yn[colbase + (jt + 3) * 16 + l15];
      MFMA_TILE(b0h0, b0h1, b0l0, b0l1, Pc1a, Pc2a, Pc1b, Pc2b);
      EPILOGUE(jt + 1, Qc1a, Qc2a, Qc1b, Qc2b, ycur);
    }
  }
  // step 14: MFMA tile 15 (buf1), epilogue tile 14 (P); no prefetch
  {
    MFMA_TILE(b1h0, b1h1, b1l0, b1l1, Qc1a, Qc2a, Qc1b, Qc2b);
    EPILOGUE(14, Pc1a, Pc2a, Pc1b, Pc2b, y0n);
  }
  // step 15: epilogue tile 15 (Q) only
  EPILOGUE(15, Qc1a, Qc2a, Qc1b, Qc2b, y1n);

#undef MFMA_TILE
#undef EPILOGUE

  // ---- row reduce: one butterfly over the 16 lane-columns, once per kernel ----
  unsigned long long rkk[8];
  #pragma unroll
  for (int s = 0; s < 8; ++s)
    rkk[s] = ((unsigned long long)f2key(rmax[s]) << 32) |
             (unsigned long long)(unsigned)(~(unsigned)ridx[s]);
  #pragma unroll
  for (int off = 1; off < 16; off <<= 1) {
    #pragma unroll
    for (int s = 0; s < 8; ++s) {
      rsum[s] += __shfl_xor(rsum[s], off);
      unsigned long long o = __shfl_xor(rkk[s], off);
      if (o > rkk[s]) rkk[s] = o;
    }
  }
  if (l15 == 0) {
    #pragma unroll
    for (int s = 0; s < 8; ++s) {
      int row = ro + ((s >> 2) << 4) + (s & 3);
      row_part_key[(size_t)blockIdx.x * NROWS + row] = rkk[s];
      row_part_sum[(size_t)blockIdx.x * NROWS + row] = rsum[s];
    }
  }

  // ---- block-level col flush: plain coalesced stores of the block partial ----
  __syncthreads();
  {
    int col = colbase + threadIdx.x;
    col_part_key[(size_t)blockIdx.y * MCOLS + col] = lkey[threadIdx.x];
    col_part_sum[(size_t)blockIdx.y * MCOLS + col] = lsum[threadIdx.x];
  }
}

// ---------- reduce row partials: 8 lanes/row, 4 partials each, shfl tree ----
__global__ __launch_bounds__(256) void reduce_rows_kernel(
    const unsigned long long* __restrict__ rpk,
    const float* __restrict__ rps,
    unsigned long long* __restrict__ row_key,
    float* __restrict__ row_sum)
{
  const int t   = blockIdx.x * 256 + threadIdx.x;   // 0 .. 65535
  const int row = t >> 3;
  const int i   = t & 7;
  unsigned long long best = 0ull; float sum = 0.0f;
  #pragma unroll
  for (int k = 0; k < 4; ++k) {
    const int bx = i + k * 8;
    unsigned long long kk = rpk[(size_t)bx * NROWS + row];
    if (kk > best) best = kk;
    sum += rps[(size_t)bx * NROWS + row];
  }
  #pragma unroll
  for (int off = 1; off < 8; off <<= 1) {
    sum += __shfl_xor(sum, off);
    unsigned long long o = __shfl_xor(best, off);
    if (o > best) best = o;
  }
  if (i == 0) { row_key[row] = best; row_sum[row] = sum; }
}

// ---------- finalize: 8 lanes/col over 64 partials, mutual test, outputs ----
__global__ __launch_bounds__(256) void finalize_kernel(
    const unsigned long long* __restrict__ row_key,
    const float* __restrict__ row_sum,
    const unsigned long long* __restrict__ cpk,
    const float* __restrict__ cps,
    float* __restrict__ out)
{
  const int t = blockIdx.x * 256 + threadIdx.x;     // 0 .. 65535
  const int j = t >> 3;
  const int i = t & 7;

  unsigned long long ck = 0ull; float csum = 0.0f;
  #pragma unroll
  for (int k = 0; k < 8; ++k) {
    const int by = i + k * 8;
    unsigned long long kk = cpk[(size_t)by * MCOLS + j];
    if (kk > ck) ck = kk;
    csum += cps[(size_t)by * MCOLS + j];
  }
  #pragma unroll
  for (int off = 1; off < 8; off <<= 1) {
    csum += __shfl_xor(csum, off);
    unsigned long long o = __shfl_xor(ck, off);
    if (o > ck) ck = o;
  }
  if (i != 0) return;

  int   ci   = (int)(~(unsigned)ck);
  float cmax = key2f((unsigned)(ck >> 32));
  float lp_col = cmax - logf(csum);

  unsigned long long rk = row_key[ci];
  int   rj   = (int)(~(unsigned)rk);
  float rmax = key2f((unsigned)(rk >> 32));
  float lp_row = rmax - logf(row_sum[ci]);

  int mut = (rj == j);
  out[j]                 = mut ? (lp_row + lp_col) : 0.0f;
  out[MCOLS + 2 * j + 0] = (float)ci;
  out[MCOLS + 2 * j + 1] = (float)j;
  out[3 * MCOLS + j]     = mut ? 1.0f : 0.0f;
}

extern "C" void kernel_launch(void* const* d_in, const int* in_sizes, int n_in,
                              void* d_out, int out_size, void* d_ws, size_t ws_size,
                              hipStream_t stream) {
  const float* x = (const float*)d_in[0];
  const float* y = (const float*)d_in[1];
  float* out = (float*)d_out;

  char* ws = (char*)d_ws;
  // layout (bytes):
  unsigned long long* row_key = (unsigned long long*)(ws);              //   0      64 KB
  float* row_sum = (float*)(ws + 65536);                                //  64K     32 KB
  float* xn      = (float*)(ws + 98304);                                //  96K     32 KB
  float* yn      = (float*)(ws + 131072);                               // 128K     32 KB
  unsigned long long* rpk = (unsigned long long*)(ws + 163840);         // 160K      2 MB
  float* rps     = (float*)(ws + 2260992);                              //           1 MB
  unsigned long long* cpk = (unsigned long long*)(ws + 3309568);        //           4 MB
  float* cps     = (float*)(ws + 7503872);                              //           2 MB
  _Float16* xh = (_Float16*)(ws + 9601024);                             //           1 MB
  _Float16* xl = (_Float16*)(ws + 10649600);                            //           1 MB
  _Float16* yh = (_Float16*)(ws + 11698176);                            //           1 MB
  _Float16* yl = (_Float16*)(ws + 12746752);                            //           1 MB
                                                                        // end ~13.2 MB

  convert_kernel<<<512, 256, 0, stream>>>(x, y, xh, xl, yh, yl, xn, yn);
  dim3 grid(MCOLS / 256, NROWS / 128);     // 32 x 64 blocks, 256 threads
  mfma_tile_kernel<<<grid, 256, 0, stream>>>(xh, xl, yh, yl, xn, yn,
                                             rpk, rps, cpk, cps);
  reduce_rows_kernel<<<256, 256, 0, stream>>>(rpk, rps, row_key, row_sum);
  finalize_kernel<<<256, 256, 0, stream>>>(row_key, row_sum, cpk, cps, out);
}

// Round 6
// 122.872 us; speedup vs baseline: 1.1696x; 1.1696x over previous
//
#include <hip/hip_runtime.h>
#include <stdint.h>

#define NROWS 8192
#define MCOLS 8192
#define DDIM  64
#define NBX   32     // grid.x (col-tile blocks) -> partials per row
#define NBY   64     // grid.y (row-tile blocks) -> partials per col

typedef _Float16 half8   __attribute__((ext_vector_type(8)));
typedef float    floatx4 __attribute__((ext_vector_type(4)));

// ---------- monotone float <-> uint key (for max-reduce argmax) ----------
__device__ __forceinline__ unsigned f2key(float f) {
  unsigned u = __float_as_uint(f);
  return (u & 0x80000000u) ? ~u : (u | 0x80000000u);
}
__device__ __forceinline__ float key2f(unsigned k) {
  unsigned u = (k & 0x80000000u) ? (k & 0x7fffffffu) : ~k;
  return __uint_as_float(u);
}

// ---------- fused: fp16-split conversion + row norms ----------
__global__ void convert_kernel(const float* __restrict__ x, const float* __restrict__ y,
                               _Float16* __restrict__ xh, _Float16* __restrict__ xl,
                               _Float16* __restrict__ yh, _Float16* __restrict__ yl,
                               float* __restrict__ xn, float* __restrict__ yn) {
  __shared__ float lnorm[32];
  const int gid = blockIdx.x * 256 + threadIdx.x;      // 0 .. 131071
  if (threadIdx.x < 32) lnorm[threadIdx.x] = 0.0f;
  __syncthreads();

  const float* src; _Float16 *dh, *dl; float* nout; int t, rowbase;
  if (gid < 65536) { src = x; dh = xh; dl = xl; nout = xn; t = gid;
                     rowbase = blockIdx.x * 32; }
  else             { src = y; dh = yh; dl = yl; nout = yn; t = gid - 65536;
                     rowbase = (blockIdx.x - 256) * 32; }

  const int lane = t & 63;
  const int c    = (t >> 6) & 1;
  const int p    = t >> 7;
  const int row  = p * 16 + (lane & 15);
  const int k0   = c * 32 + ((lane >> 4) << 3);
  const float* s = src + (size_t)row * DDIM + k0;

  float fb[8];
  *(floatx4*)(&fb[0]) = *(const floatx4*)(s);
  *(floatx4*)(&fb[4]) = *(const floatx4*)(s + 4);

  _Float16 hbuf[8], lbuf[8];
  float s8 = 0.0f;
  #pragma unroll
  for (int j = 0; j < 8; ++j) {
    float f = fb[j];
    _Float16 h = (_Float16)f;
    hbuf[j] = h;
    lbuf[j] = (_Float16)((f - (float)h) * 2048.0f);
    s8 = fmaf(f, f, s8);
  }
  size_t o = (size_t)t * 8;
  *(half8*)(dh + o) = *(half8*)hbuf;
  *(half8*)(dl + o) = *(half8*)lbuf;

  atomicAdd(&lnorm[((p & 1) << 4) | (t & 15)], s8);
  __syncthreads();
  if (threadIdx.x < 32) nout[rowbase + threadIdx.x] = lnorm[threadIdx.x];
}

#define MFMA16(A, B, C) __builtin_amdgcn_mfma_f32_16x16x32_f16((A), (B), (C), 0, 0, 0)

// ---------- main pass: block = 4 waves, each wave 32 rows x 256 cols ----------
// Round-6: REVERT launch bounds to (256,3).  Round-5's (256,4) forced the
// allocator to 64 arch VGPRs, far below the ~112-reg live set -> scratch
// spill (WRITE_SIZE 9.2 -> 81 MB, FETCH 9.4 -> 52 MB, main 66 -> 92+ us).
// 3 blocks/CU is the feasible max for this footprint; occupancy lever CLOSED.
// Everything else = round-5 source (8-lane reducers kept, round-2 epilogue).
__global__ __launch_bounds__(256, 3) void mfma_tile_kernel(
    const _Float16* __restrict__ xh, const _Float16* __restrict__ xl,
    const _Float16* __restrict__ yh, const _Float16* __restrict__ yl,
    const float* __restrict__ xn, const float* __restrict__ yn,
    unsigned long long* __restrict__ row_part_key, float* __restrict__ row_part_sum,
    unsigned long long* __restrict__ col_part_key, float* __restrict__ col_part_sum)
{
  __shared__ unsigned long long lkey[256];   // per-block col keys (2 KB)
  __shared__ float              lsum[256];   // per-block col sums (1 KB)

  const int wave = threadIdx.x >> 6;
  const int lane = threadIdx.x & 63;
  const int l15  = lane & 15;
  const int g    = lane >> 4;                // row-group 0..3
  const int ap0  = blockIdx.y * 8 + wave * 2;       // first of 2 A panels
  const int ro   = ap0 * 16 + g * 4;                // first row this lane covers
  const int colbase = blockIdx.x * 256;

  lkey[threadIdx.x] = 0ull;
  lsum[threadIdx.x] = 0.0f;
  __syncthreads();

  // ---- A fragments: 2 panels x (2 hi + 2 lo chunks), 32 VGPRs ----
  const half8* xh8 = (const half8*)xh;
  const half8* xl8 = (const half8*)xl;
  const half8* yh8 = (const half8*)yh;
  const half8* yl8 = (const half8*)yl;
  const size_t a0 = (size_t)ap0 * 128 + lane;
  half8 Ah[2][2], Al[2][2];
  #pragma unroll
  for (int p = 0; p < 2; ++p) {
    Ah[p][0] = xh8[a0 + p * 128];      Ah[p][1] = xh8[a0 + p * 128 + 64];
    Al[p][0] = xl8[a0 + p * 128];      Al[p][1] = xl8[a0 + p * 128 + 64];
  }

  // ---- per-row state: 8 rows/lane ----
  float xne[8], rsum[8], rmax[8]; int ridx[8];
  #pragma unroll
  for (int s = 0; s < 8; ++s) {
    xne[s]  = xn[ro + ((s >> 2) << 4) + (s & 3)];
    rsum[s] = 0.0f; rmax[s] = -3.4e38f; ridx[s] = 0;
  }

  const size_t bcol0 = (size_t)(blockIdx.x * 16) * 128 + lane;

  // ---- double-buffered B fragments + column norms ----
  half8 b0h0, b0h1, b0l0, b0l1; float y0n;
  half8 b1h0, b1h1, b1l0, b1l1; float y1n;
  b0h0 = yh8[bcol0];        b0h1 = yh8[bcol0 + 64];
  b0l0 = yl8[bcol0];        b0l1 = yl8[bcol0 + 64];
  y0n  = yn[colbase + l15];
  b1h0 = yh8[bcol0 + 128];  b1h1 = yh8[bcol0 + 192];
  b1l0 = yl8[bcol0 + 128];  b1l1 = yl8[bcol0 + 192];
  y1n  = yn[colbase + 16 + l15];

#define MFMA_TILE(BH0, BH1, BL0, BL1, O1A, O2A, O1B, O2B)                      \
  {                                                                            \
    floatx4 c1_ = {}, c2_ = {};                                                \
    c1_ = MFMA16(Ah[0][0], BH0, c1_);                                          \
    c1_ = MFMA16(Ah[0][1], BH1, c1_);                                          \
    c2_ = MFMA16(Al[0][0], BH0, c2_);                                          \
    c2_ = MFMA16(Al[0][1], BH1, c2_);                                          \
    c2_ = MFMA16(Ah[0][0], BL0, c2_);                                          \
    c2_ = MFMA16(Ah[0][1], BL1, c2_);                                          \
    O1A = c1_; O2A = c2_;                                                      \
    floatx4 d1_ = {}, d2_ = {};                                                \
    d1_ = MFMA16(Ah[1][0], BH0, d1_);                                          \
    d1_ = MFMA16(Ah[1][1], BH1, d1_);                                          \
    d2_ = MFMA16(Al[1][0], BH0, d2_);                                          \
    d2_ = MFMA16(Al[1][1], BH1, d2_);                                          \
    d2_ = MFMA16(Ah[1][0], BL0, d2_);                                          \
    d2_ = MFMA16(Ah[1][1], BL1, d2_);                                          \
    O1B = d1_; O2B = d2_;                                                      \
  }

#define EPILOGUE(JT, C1A, C2A, C1B, C2B, YNC)                                  \
  {                                                                            \
    const int col_ = colbase + (JT) * 16 + l15;                                \
    float cmax_ = -3.4e38f; int cidx_ = 0;                                     \
    float epan0_, epan1_;                                                      \
    {                                                                          \
      float ee_[4];                                                            \
      _Pragma("unroll")                                                        \
      for (int r = 0; r < 4; ++r) {                                            \
        const int s_ = r;                                                      \
        float dot = fmaf(C2A[r], (1.0f / 2048.0f), C1A[r]);                    \
        float sq  = fmaxf(fmaf(-2.0f, dot, xne[s_] + (YNC)), 0.0f);            \
        float d   = 2.0f - __builtin_amdgcn_sqrtf(sq);                         \
        float e   = __expf(d);                                                 \
        rsum[s_] += e;                                                         \
        if (d > rmax[s_]) ridx[s_] = col_;   /* cols ascend -> first max */    \
        rmax[s_] = fmaxf(rmax[s_], d);                                         \
        if (d > cmax_) cidx_ = s_;           /* rows ascend -> first max */    \
        cmax_ = fmaxf(cmax_, d);                                               \
        ee_[r] = e;                                                            \
      }                                                                        \
      epan0_ = (ee_[0] + ee_[1]) + (ee_[2] + ee_[3]);                          \
    }                                                                          \
    {                                                                          \
      float ee_[4];                                                            \
      _Pragma("unroll")                                                        \
      for (int r = 0; r < 4; ++r) {                                            \
        const int s_ = 4 + r;                                                  \
        float dot = fmaf(C2B[r], (1.0f / 2048.0f), C1B[r]);                    \
        float sq  = fmaxf(fmaf(-2.0f, dot, xne[s_] + (YNC)), 0.0f);            \
        float d   = 2.0f - __builtin_amdgcn_sqrtf(sq);                         \
        float e   = __expf(d);                                                 \
        rsum[s_] += e;                                                         \
        if (d > rmax[s_]) ridx[s_] = col_;                                     \
        rmax[s_] = fmaxf(rmax[s_], d);                                         \
        if (d > cmax_) cidx_ = s_;                                             \
        cmax_ = fmaxf(cmax_, d);                                               \
        ee_[r] = e;                                                            \
      }                                                                        \
      epan1_ = (ee_[0] + ee_[1]) + (ee_[2] + ee_[3]);                          \
    }                                                                          \
    float csum_ = epan0_ + epan1_;         /* same sum tree as before */       \
    int crow_ = ro + ((cidx_ >> 2) << 4) + (cidx_ & 3);                        \
    unsigned long long ckey_ =                                                 \
        ((unsigned long long)f2key(cmax_) << 32) |                             \
        (unsigned long long)(unsigned)(~(unsigned)crow_);                      \
    atomicMax(&lkey[(JT) * 16 + l15], ckey_);   /* ds_max_u64 */               \
    atomicAdd(&lsum[(JT) * 16 + l15], csum_);   /* ds_add_f32 */               \
  }

  // ---- results pipeline: P = current tile, Q = next tile ----
  floatx4 Pc1a, Pc2a, Pc1b, Pc2b;
  floatx4 Qc1a, Qc2a, Qc1b, Qc2b;

  MFMA_TILE(b0h0, b0h1, b0l0, b0l1, Pc1a, Pc2a, Pc1b, Pc2b);   // tile 0

  for (int jt = 0; jt < 14; jt += 2) {
    // even step: MFMA tile jt+1 (buf1), epilogue tile jt (P), prefetch jt+2->buf0
    {
      float ycur = y0n;
      const size_t bn = bcol0 + (size_t)(jt + 2) * 128;
      b0h0 = yh8[bn];      b0h1 = yh8[bn + 64];
      b0l0 = yl8[bn];      b0l1 = yl8[bn + 64];
      y0n  = yn[colbase + (jt + 2) * 16 + l15];
      MFMA_TILE(b1h0, b1h1, b1l0, b1l1, Qc1a, Qc2a, Qc1b, Qc2b);
      EPILOGUE(jt, Pc1a, Pc2a, Pc1b, Pc2b, ycur);
    }
    // odd step: MFMA tile jt+2 (buf0), epilogue tile jt+1 (Q), prefetch jt+3->buf1
    {
      float ycur = y1n;
      const size_t bn = bcol0 + (size_t)(jt + 3) * 128;
      b1h0 = yh8[bn];      b1h1 = yh8[bn + 64];
      b1l0 = yl8[bn];      b1l1 = yl8[bn + 64];
      y1n  = yn[colbase + (jt + 3) * 16 + l15];
      MFMA_TILE(b0h0, b0h1, b0l0, b0l1, Pc1a, Pc2a, Pc1b, Pc2b);
      EPILOGUE(jt + 1, Qc1a, Qc2a, Qc1b, Qc2b, ycur);
    }
  }
  // step 14: MFMA tile 15 (buf1), epilogue tile 14 (P); no prefetch
  {
    MFMA_TILE(b1h0, b1h1, b1l0, b1l1, Qc1a, Qc2a, Qc1b, Qc2b);
    EPILOGUE(14, Pc1a, Pc2a, Pc1b, Pc2b, y0n);
  }
  // step 15: epilogue tile 15 (Q) only
  EPILOGUE(15, Qc1a, Qc2a, Qc1b, Qc2b, y1n);

#undef MFMA_TILE
#undef EPILOGUE

  // ---- row reduce: one butterfly over the 16 lane-columns, once per kernel ----
  unsigned long long rkk[8];
  #pragma unroll
  for (int s = 0; s < 8; ++s)
    rkk[s] = ((unsigned long long)f2key(rmax[s]) << 32) |
             (unsigned long long)(unsigned)(~(unsigned)ridx[s]);
  #pragma unroll
  for (int off = 1; off < 16; off <<= 1) {
    #pragma unroll
    for (int s = 0; s < 8; ++s) {
      rsum[s] += __shfl_xor(rsum[s], off);
      unsigned long long o = __shfl_xor(rkk[s], off);
      if (o > rkk[s]) rkk[s] = o;
    }
  }
  if (l15 == 0) {
    #pragma unroll
    for (int s = 0; s < 8; ++s) {
      int row = ro + ((s >> 2) << 4) + (s & 3);
      row_part_key[(size_t)blockIdx.x * NROWS + row] = rkk[s];
      row_part_sum[(size_t)blockIdx.x * NROWS + row] = rsum[s];
    }
  }

  // ---- block-level col flush: plain coalesced stores of the block partial ----
  __syncthreads();
  {
    int col = colbase + threadIdx.x;
    col_part_key[(size_t)blockIdx.y * MCOLS + col] = lkey[threadIdx.x];
    col_part_sum[(size_t)blockIdx.y * MCOLS + col] = lsum[threadIdx.x];
  }
}

// ---------- reduce row partials: 8 lanes/row, 4 partials each, shfl tree ----
__global__ __launch_bounds__(256) void reduce_rows_kernel(
    const unsigned long long* __restrict__ rpk,
    const float* __restrict__ rps,
    unsigned long long* __restrict__ row_key,
    float* __restrict__ row_sum)
{
  const int t   = blockIdx.x * 256 + threadIdx.x;   // 0 .. 65535
  const int row = t >> 3;
  const int i   = t & 7;
  unsigned long long best = 0ull; float sum = 0.0f;
  #pragma unroll
  for (int k = 0; k < 4; ++k) {
    const int bx = i + k * 8;
    unsigned long long kk = rpk[(size_t)bx * NROWS + row];
    if (kk > best) best = kk;
    sum += rps[(size_t)bx * NROWS + row];
  }
  #pragma unroll
  for (int off = 1; off < 8; off <<= 1) {
    sum += __shfl_xor(sum, off);
    unsigned long long o = __shfl_xor(best, off);
    if (o > best) best = o;
  }
  if (i == 0) { row_key[row] = best; row_sum[row] = sum; }
}

// ---------- finalize: 8 lanes/col over 64 partials, mutual test, outputs ----
__global__ __launch_bounds__(256) void finalize_kernel(
    const unsigned long long* __restrict__ row_key,
    const float* __restrict__ row_sum,
    const unsigned long long* __restrict__ cpk,
    const float* __restrict__ cps,
    float* __restrict__ out)
{
  const int t = blockIdx.x * 256 + threadIdx.x;     // 0 .. 65535
  const int j = t >> 3;
  const int i = t & 7;

  unsigned long long ck = 0ull; float csum = 0.0f;
  #pragma unroll
  for (int k = 0; k < 8; ++k) {
    const int by = i + k * 8;
    unsigned long long kk = cpk[(size_t)by * MCOLS + j];
    if (kk > ck) ck = kk;
    csum += cps[(size_t)by * MCOLS + j];
  }
  #pragma unroll
  for (int off = 1; off < 8; off <<= 1) {
    csum += __shfl_xor(csum, off);
    unsigned long long o = __shfl_xor(ck, off);
    if (o > ck) ck = o;
  }
  if (i != 0) return;

  int   ci   = (int)(~(unsigned)ck);
  float cmax = key2f((unsigned)(ck >> 32));
  float lp_col = cmax - logf(csum);

  unsigned long long rk = row_key[ci];
  int   rj   = (int)(~(unsigned)rk);
  float rmax = key2f((unsigned)(rk >> 32));
  float lp_row = rmax - logf(row_sum[ci]);

  int mut = (rj == j);
  out[j]                 = mut ? (lp_row + lp_col) : 0.0f;
  out[MCOLS + 2 * j + 0] = (float)ci;
  out[MCOLS + 2 * j + 1] = (float)j;
  out[3 * MCOLS + j]     = mut ? 1.0f : 0.0f;
}

extern "C" void kernel_launch(void* const* d_in, const int* in_sizes, int n_in,
                              void* d_out, int out_size, void* d_ws, size_t ws_size,
                              hipStream_t stream) {
  const float* x = (const float*)d_in[0];
  const float* y = (const float*)d_in[1];
  float* out = (float*)d_out;

  char* ws = (char*)d_ws;
  // layout (bytes):
  unsigned long long* row_key = (unsigned long long*)(ws);              //   0      64 KB
  float* row_sum = (float*)(ws + 65536);                                //  64K     32 KB
  float* xn      = (float*)(ws + 98304);                                //  96K     32 KB
  float* yn      = (float*)(ws + 131072);                               // 128K     32 KB
  unsigned long long* rpk = (unsigned long long*)(ws + 163840);         // 160K      2 MB
  float* rps     = (float*)(ws + 2260992);                              //           1 MB
  unsigned long long* cpk = (unsigned long long*)(ws + 3309568);        //           4 MB
  float* cps     = (float*)(ws + 7503872);                              //           2 MB
  _Float16* xh = (_Float16*)(ws + 9601024);                             //           1 MB
  _Float16* xl = (_Float16*)(ws + 10649600);                            //           1 MB
  _Float16* yh = (_Float16*)(ws + 11698176);                            //           1 MB
  _Float16* yl = (_Float16*)(ws + 12746752);                            //           1 MB
                                                                        // end ~13.2 MB

  convert_kernel<<<512, 256, 0, stream>>>(x, y, xh, xl, yh, yl, xn, yn);
  dim3 grid(MCOLS / 256, NROWS / 128);     // 32 x 64 blocks, 256 threads
  mfma_tile_kernel<<<grid, 256, 0, stream>>>(xh, xl, yh, yl, xn, yn,
                                             rpk, rps, cpk, cps);
  reduce_rows_kernel<<<256, 256, 0, stream>>>(rpk, rps, row_key, row_sum);
  finalize_kernel<<<256, 256, 0, stream>>>(row_key, row_sum, cpk, cps, out);
}